// Round 4
// baseline (218.167 us; speedup 1.0000x reference)
//
#include <hip/hip_runtime.h>
#include <math.h>

#define MM 8
#define SS 4
#define NLEAF 20
#define KINT 19
#define NBR 38                   // total branches: 2 + 18*2
#define P4 (NBR*MM*4)            // float4 count of P region = 1216
#define PFLOATS (P4*4)           // 4864 floats
#define NNODE 39
#define SPT 8                    // sites per thread
#define SPB 512                  // sites per block (64 lanes * SPT)

typedef float v2f __attribute__((ext_vector_type(2)));
typedef float v4f __attribute__((ext_vector_type(4)));

// ---------------- setup: Q build + 304 small expm (fp64), stores P TRANSPOSED ----------------

__device__ __forceinline__ void mat4_mul(const double a[4][4], const double b[4][4], double c[4][4]) {
    #pragma unroll
    for (int i = 0; i < 4; i++)
        #pragma unroll
        for (int j = 0; j < 4; j++) {
            double s = 0.0;
            #pragma unroll
            for (int k = 0; k < 4; k++) s += a[i][k] * b[k][j];
            c[i][j] = s;
        }
}

__global__ void setup_kernel(const float* __restrict__ rates,
                             const float* __restrict__ pi_inv,
                             const float* __restrict__ rho,
                             const float* __restrict__ T,
                             float* __restrict__ ws)   // [NBR][MM][4][4] P^T, then pi[MM][4]
{
    int tid = blockIdx.x * blockDim.x + threadIdx.x;
    if (tid >= NBR * MM) return;
    int m = tid & 7;
    int k = tid >> 3;

    // pi = inv_stereographic_projection(pi_inv)^2
    double y0 = pi_inv[m*3+0], y1 = pi_inv[m*3+1], y2 = pi_inv[m*3+2];
    double ns  = y0*y0 + y1*y1 + y2*y2;
    double inv = 1.0 / (ns + 1.0);
    double p[4] = {2.0*y0*inv, 2.0*y1*inv, 2.0*y2*inv, (ns-1.0)*inv};
    #pragma unroll
    for (int i = 0; i < 4; i++) p[i] *= p[i];

    if (k == 0) {
        #pragma unroll
        for (int i = 0; i < 4; i++) ws[PFLOATS + m*4 + i] = (float)p[i];
    }

    // Q from squared rates
    double r[6];
    #pragma unroll
    for (int i = 0; i < 6; i++) { double v = rates[m*6+i]; r[i] = v*v; }
    double Q[4][4] = {};
    Q[0][1]=r[0]; Q[0][2]=r[1]; Q[0][3]=r[2]; Q[1][2]=r[3]; Q[1][3]=r[4]; Q[2][3]=r[5];
    #pragma unroll
    for (int i = 0; i < 4; i++)
        #pragma unroll
        for (int j = i+1; j < 4; j++) Q[j][i] = Q[i][j];
    #pragma unroll
    for (int i = 0; i < 4; i++)
        #pragma unroll
        for (int j = 0; j < 4; j++) Q[i][j] *= p[j];
    double emut = 0.0;
    #pragma unroll
    for (int i = 0; i < 4; i++) {
        double rs = 0.0;
        #pragma unroll
        for (int j = 0; j < 4; j++) if (j != i) rs += Q[i][j];
        Q[i][i] = -rs;
        emut += p[i] * rs;
    }
    emut = fmax(emut, 1e-9);
    double scq = (double)rho[m] / emut;

    // branch length for branch k (caterpillar)
    double t;
    if      (k == 0) t = T[0*NNODE + NLEAF];
    else if (k == 1) t = T[1*NNODE + NLEAF];
    else {
        int j     = k >> 1;                       // 1..18
        int node  = NLEAF + j;
        int child = (k & 1) ? (j + 1) : (NLEAF - 1 + j);
        t = T[child*NNODE + node];
    }

    double A[4][4];
    #pragma unroll
    for (int i = 0; i < 4; i++)
        #pragma unroll
        for (int j = 0; j < 4; j++) A[i][j] = Q[i][j] * scq * t;

    // expm: scale to norm <= 2^-4, Taylor(9), square back
    double nrm = 0.0;
    #pragma unroll
    for (int i = 0; i < 4; i++) {
        double rs = 0.0;
        #pragma unroll
        for (int j = 0; j < 4; j++) rs += fabs(A[i][j]);
        nrm = fmax(nrm, rs);
    }
    int s = 0;
    if (nrm > 0.0625) s = (int)ceil(log2(nrm * 16.0));
    if (s < 0) s = 0;
    if (s > 60) s = 60;
    double scl = ldexp(1.0, -s);
    double B[4][4];
    #pragma unroll
    for (int i = 0; i < 4; i++)
        #pragma unroll
        for (int j = 0; j < 4; j++) B[i][j] = A[i][j] * scl;

    double E[4][4];
    #pragma unroll
    for (int i = 0; i < 4; i++)
        #pragma unroll
        for (int j = 0; j < 4; j++) E[i][j] = (i == j) ? 1.0 : 0.0;
    for (int kk = 9; kk >= 1; --kk) {
        double Tm[4][4];
        mat4_mul(B, E, Tm);
        double ik = 1.0 / (double)kk;
        #pragma unroll
        for (int i = 0; i < 4; i++)
            #pragma unroll
            for (int j = 0; j < 4; j++) E[i][j] = ((i == j) ? 1.0 : 0.0) + Tm[i][j] * ik;
    }
    for (int q = 0; q < s; q++) {
        double Tm[4][4];
        mat4_mul(E, E, Tm);
        #pragma unroll
        for (int i = 0; i < 4; i++)
            #pragma unroll
            for (int j = 0; j < 4; j++) E[i][j] = Tm[i][j];
    }

    // TRANSPOSED store: Pout[d*4 + c] = E[c][d]  => float4 at offset d is column d of P
    float* Pout = ws + (k*MM + m) * 16;
    #pragma unroll
    for (int d = 0; d < 4; d++)
        #pragma unroll
        for (int c = 0; c < 4; c++) Pout[d*4+c] = (float)E[c][d];
}

// ---------------- main: wave = mixture, 8 sites/thread, packed fp32 ----------------

#define SHUF(v,a,b) __builtin_shufflevector((v),(v),(a),(b))

// result[c] = sum_d col_d[c] * x[d];  outputs pair-packed: lo={r0,r1}, hi={r2,r3}
__device__ __forceinline__ void matvx(const v4f& c0, const v4f& c1, const v4f& c2, const v4f& c3,
                                      const v4f& x, v2f& lo, v2f& hi)
{
    v2f l = SHUF(c0,0,1) * SHUF(x,0,0);
    v2f h = SHUF(c0,2,3) * SHUF(x,0,0);
    l = __builtin_elementwise_fma(SHUF(c1,0,1), SHUF(x,1,1), l);
    h = __builtin_elementwise_fma(SHUF(c1,2,3), SHUF(x,1,1), h);
    l = __builtin_elementwise_fma(SHUF(c2,0,1), SHUF(x,2,2), l);
    h = __builtin_elementwise_fma(SHUF(c2,2,3), SHUF(x,2,2), h);
    l = __builtin_elementwise_fma(SHUF(c3,0,1), SHUF(x,3,3), l);
    h = __builtin_elementwise_fma(SHUF(c3,2,3), SHUF(x,3,3), h);
    lo = l; hi = h;
}

// same but operand vector is the pair-packed state {alo=(A0,A1), ahi=(A2,A3)}
__device__ __forceinline__ void matvs(const v4f& c0, const v4f& c1, const v4f& c2, const v4f& c3,
                                      v2f alo, v2f ahi, v2f& lo, v2f& hi)
{
    v2f l = SHUF(c0,0,1) * SHUF(alo,0,0);
    v2f h = SHUF(c0,2,3) * SHUF(alo,0,0);
    l = __builtin_elementwise_fma(SHUF(c1,0,1), SHUF(alo,1,1), l);
    h = __builtin_elementwise_fma(SHUF(c1,2,3), SHUF(alo,1,1), h);
    l = __builtin_elementwise_fma(SHUF(c2,0,1), SHUF(ahi,0,0), l);
    h = __builtin_elementwise_fma(SHUF(c2,2,3), SHUF(ahi,0,0), h);
    l = __builtin_elementwise_fma(SHUF(c3,0,1), SHUF(ahi,1,1), l);
    h = __builtin_elementwise_fma(SHUF(c3,2,3), SHUF(ahi,1,1), h);
    lo = l; hi = h;
}

#define LOADX(B, LEAF) { _Pragma("unroll") for (int k = 0; k < SPT; k++) B[k] = xp[k][(LEAF)]; }

#define STEP(J, XB) { \
    const v4f* PI = &Pl[((2*(J))*MM + m)*4]; \
    const v4f* PL = PI + MM*4; \
    v4f ci0=PI[0], ci1=PI[1], ci2=PI[2], ci3=PI[3]; \
    v4f cl0=PL[0], cl1=PL[1], cl2=PL[2], cl3=PL[3]; \
    _Pragma("unroll") for (int k = 0; k < SPT; k++) { \
        v2f tl, th, ul, uh; \
        matvs(ci0,ci1,ci2,ci3, lo[k], hi[k], tl, th); \
        matvx(cl0,cl1,cl2,cl3, XB[k], ul, uh); \
        lo[k] = tl*ul; hi[k] = th*uh; \
    } }

__global__ __launch_bounds__(512) void phylo_kernel(const float* __restrict__ X,
                                                    const float* __restrict__ ws,
                                                    float* __restrict__ out,
                                                    int batch)
{
    __shared__ v4f Pl[P4 + MM];
    const v4f* w4 = (const v4f*)ws;
    for (int idx = threadIdx.x; idx < P4 + MM; idx += 512) Pl[idx] = w4[idx];
    __syncthreads();

    const int lane = threadIdx.x & 63;
    const int m    = threadIdx.x >> 6;        // wave index == mixture index
    const int siteBase = blockIdx.x * SPB;

    // per-k base pointers (clamped for the partial last block)
    const v4f* xp[SPT];
    #pragma unroll
    for (int k = 0; k < SPT; k++) {
        int s = siteBase + lane + 64*k;
        if (s >= batch) s = batch - 1;
        xp[k] = (const v4f*)X + (size_t)s * 20;
    }

    v2f lo[SPT], hi[SPT];

    // ---- step 0: node 20 = (leaf0, leaf1) ----
    v4f XA[SPT], XB[SPT];
    LOADX(XA, 0);
    LOADX(XB, 1);
    {
        const v4f* P0 = &Pl[(0*MM + m)*4];
        const v4f* P1 = P0 + MM*4;
        v4f a0=P0[0], a1=P0[1], a2=P0[2], a3=P0[3];
        v4f e0=P1[0], e1=P1[1], e2=P1[2], e3=P1[3];
        #pragma unroll
        for (int k = 0; k < SPT; k++) {
            v2f tl, th, ul, uh;
            matvx(a0,a1,a2,a3, XA[k], tl, th);
            matvx(e0,e1,e2,e3, XB[k], ul, uh);
            lo[k] = tl*ul; hi[k] = th*uh;
        }
    }

    // ---- steps 1..18, double-buffered X leaf loads ----
    LOADX(XA, 2);                       // leaf for step j=1
    #pragma unroll 1
    for (int jj = 0; jj < 9; ++jj) {
        int jA = 1 + 2*jj;
        LOADX(XB, 3 + 2*jj);            // leaf for step jA+1
        STEP(jA, XA);
        if (jj < 8) LOADX(XA, 4 + 2*jj); // leaf for next jA
        STEP(jA + 1, XB);
    }

    // ---- epilogue: out[site, m] = sum_c A[c] * pi[m][c] ----
    v4f pim = Pl[P4 + m];
    v2f plo = SHUF(pim,0,1), phi = SHUF(pim,2,3);
    #pragma unroll
    for (int k = 0; k < SPT; k++) {
        v2f s = __builtin_elementwise_fma(hi[k], phi, lo[k]*plo);
        float r = s.x + s.y;
        int st = siteBase + lane + 64*k;
        if (st < batch) out[(size_t)st*MM + m] = r;
    }
}

// ---------------- launch ----------------

extern "C" void kernel_launch(void* const* d_in, const int* in_sizes, int n_in,
                              void* d_out, int out_size, void* d_ws, size_t ws_size,
                              hipStream_t stream)
{
    const float* X      = (const float*)d_in[0];
    const float* rates  = (const float*)d_in[1];
    const float* pi_inv = (const float*)d_in[2];
    const float* rho    = (const float*)d_in[3];
    const float* T      = (const float*)d_in[4];
    float* out = (float*)d_out;
    float* ws  = (float*)d_ws;

    int batch = in_sizes[0] / (NLEAF * SS);

    hipLaunchKernelGGL(setup_kernel, dim3(1), dim3(320), 0, stream,
                       rates, pi_inv, rho, T, ws);

    int grid = (batch + SPB - 1) / SPB;
    hipLaunchKernelGGL(phylo_kernel, dim3(grid), dim3(512), 0, stream,
                       X, ws, out, batch);
}

// Round 6
// 146.875 us; speedup vs baseline: 1.4854x; 1.4854x over previous
//
#include <hip/hip_runtime.h>
#include <math.h>

#define MM 8
#define SS 4
#define NLEAF 20
#define KINT 19
#define NBR 38                   // total branches: 2 + 18*2
#define P4 (NBR*MM*4)            // float4 count of P region = 1216
#define PFLOATS (P4*4)           // 4864 floats
#define NNODE 39

typedef float v2f __attribute__((ext_vector_type(2)));
typedef float v4f __attribute__((ext_vector_type(4)));

// ---------------- setup: Q build + 304 small expm (fp64), stores P TRANSPOSED ----------------

__device__ __forceinline__ void mat4_mul(const double a[4][4], const double b[4][4], double c[4][4]) {
    #pragma unroll
    for (int i = 0; i < 4; i++)
        #pragma unroll
        for (int j = 0; j < 4; j++) {
            double s = 0.0;
            #pragma unroll
            for (int k = 0; k < 4; k++) s += a[i][k] * b[k][j];
            c[i][j] = s;
        }
}

__global__ void setup_kernel(const float* __restrict__ rates,
                             const float* __restrict__ pi_inv,
                             const float* __restrict__ rho,
                             const float* __restrict__ T,
                             float* __restrict__ ws)   // [NBR][MM][4][4] P^T, then pi[MM][4]
{
    int tid = blockIdx.x * blockDim.x + threadIdx.x;
    if (tid >= NBR * MM) return;
    int m = tid & 7;
    int k = tid >> 3;

    // pi = inv_stereographic_projection(pi_inv)^2
    double y0 = pi_inv[m*3+0], y1 = pi_inv[m*3+1], y2 = pi_inv[m*3+2];
    double ns  = y0*y0 + y1*y1 + y2*y2;
    double inv = 1.0 / (ns + 1.0);
    double p[4] = {2.0*y0*inv, 2.0*y1*inv, 2.0*y2*inv, (ns-1.0)*inv};
    #pragma unroll
    for (int i = 0; i < 4; i++) p[i] *= p[i];

    if (k == 0) {
        #pragma unroll
        for (int i = 0; i < 4; i++) ws[PFLOATS + m*4 + i] = (float)p[i];
    }

    // Q from squared rates
    double r[6];
    #pragma unroll
    for (int i = 0; i < 6; i++) { double v = rates[m*6+i]; r[i] = v*v; }
    double Q[4][4] = {};
    Q[0][1]=r[0]; Q[0][2]=r[1]; Q[0][3]=r[2]; Q[1][2]=r[3]; Q[1][3]=r[4]; Q[2][3]=r[5];
    #pragma unroll
    for (int i = 0; i < 4; i++)
        #pragma unroll
        for (int j = i+1; j < 4; j++) Q[j][i] = Q[i][j];
    #pragma unroll
    for (int i = 0; i < 4; i++)
        #pragma unroll
        for (int j = 0; j < 4; j++) Q[i][j] *= p[j];
    double emut = 0.0;
    #pragma unroll
    for (int i = 0; i < 4; i++) {
        double rs = 0.0;
        #pragma unroll
        for (int j = 0; j < 4; j++) if (j != i) rs += Q[i][j];
        Q[i][i] = -rs;
        emut += p[i] * rs;
    }
    emut = fmax(emut, 1e-9);
    double scq = (double)rho[m] / emut;

    // branch length for branch k (caterpillar)
    double t;
    if      (k == 0) t = T[0*NNODE + NLEAF];
    else if (k == 1) t = T[1*NNODE + NLEAF];
    else {
        int j     = k >> 1;                       // 1..18
        int node  = NLEAF + j;
        int child = (k & 1) ? (j + 1) : (NLEAF - 1 + j);
        t = T[child*NNODE + node];
    }

    double A[4][4];
    #pragma unroll
    for (int i = 0; i < 4; i++)
        #pragma unroll
        for (int j = 0; j < 4; j++) A[i][j] = Q[i][j] * scq * t;

    // expm: scale to norm <= 2^-4, Taylor(9), square back
    double nrm = 0.0;
    #pragma unroll
    for (int i = 0; i < 4; i++) {
        double rs = 0.0;
        #pragma unroll
        for (int j = 0; j < 4; j++) rs += fabs(A[i][j]);
        nrm = fmax(nrm, rs);
    }
    int s = 0;
    if (nrm > 0.0625) s = (int)ceil(log2(nrm * 16.0));
    if (s < 0) s = 0;
    if (s > 60) s = 60;
    double scl = ldexp(1.0, -s);
    double B[4][4];
    #pragma unroll
    for (int i = 0; i < 4; i++)
        #pragma unroll
        for (int j = 0; j < 4; j++) B[i][j] = A[i][j] * scl;

    double E[4][4];
    #pragma unroll
    for (int i = 0; i < 4; i++)
        #pragma unroll
        for (int j = 0; j < 4; j++) E[i][j] = (i == j) ? 1.0 : 0.0;
    for (int kk = 9; kk >= 1; --kk) {
        double Tm[4][4];
        mat4_mul(B, E, Tm);
        double ik = 1.0 / (double)kk;
        #pragma unroll
        for (int i = 0; i < 4; i++)
            #pragma unroll
            for (int j = 0; j < 4; j++) E[i][j] = ((i == j) ? 1.0 : 0.0) + Tm[i][j] * ik;
    }
    for (int q = 0; q < s; q++) {
        double Tm[4][4];
        mat4_mul(E, E, Tm);
        #pragma unroll
        for (int i = 0; i < 4; i++)
            #pragma unroll
            for (int j = 0; j < 4; j++) E[i][j] = Tm[i][j];
    }

    // TRANSPOSED store: Pout[d*4 + c] = E[c][d]  => float4 at offset d is column d of P
    float* Pout = ws + (k*MM + m) * 16;
    #pragma unroll
    for (int d = 0; d < 4; d++)
        #pragma unroll
        for (int c = 0; c < 4; c++) Pout[d*4+c] = (float)E[c][d];
}

// ---------------- main: 1 site/thread, all 8 mixtures; P via wave-uniform scalar loads ----------------

#define SHUF(v,a,b) __builtin_shufflevector((v),(v),(a),(b))

// result[c] = sum_d col_d[c] * x[d];  outputs pair-packed: lo={r0,r1}, hi={r2,r3}
__device__ __forceinline__ void matvx(const v4f& c0, const v4f& c1, const v4f& c2, const v4f& c3,
                                      const v4f& x, v2f& lo, v2f& hi)
{
    v2f l = SHUF(c0,0,1) * SHUF(x,0,0);
    v2f h = SHUF(c0,2,3) * SHUF(x,0,0);
    l = __builtin_elementwise_fma(SHUF(c1,0,1), SHUF(x,1,1), l);
    h = __builtin_elementwise_fma(SHUF(c1,2,3), SHUF(x,1,1), h);
    l = __builtin_elementwise_fma(SHUF(c2,0,1), SHUF(x,2,2), l);
    h = __builtin_elementwise_fma(SHUF(c2,2,3), SHUF(x,2,2), h);
    l = __builtin_elementwise_fma(SHUF(c3,0,1), SHUF(x,3,3), l);
    h = __builtin_elementwise_fma(SHUF(c3,2,3), SHUF(x,3,3), h);
    lo = l; hi = h;
}

// same but operand vector is the pair-packed state {alo=(A0,A1), ahi=(A2,A3)}
__device__ __forceinline__ void matvs(const v4f& c0, const v4f& c1, const v4f& c2, const v4f& c3,
                                      v2f alo, v2f ahi, v2f& lo, v2f& hi)
{
    v2f l = SHUF(c0,0,1) * SHUF(alo,0,0);
    v2f h = SHUF(c0,2,3) * SHUF(alo,0,0);
    l = __builtin_elementwise_fma(SHUF(c1,0,1), SHUF(alo,1,1), l);
    h = __builtin_elementwise_fma(SHUF(c1,2,3), SHUF(alo,1,1), h);
    l = __builtin_elementwise_fma(SHUF(c2,0,1), SHUF(ahi,0,0), l);
    h = __builtin_elementwise_fma(SHUF(c2,2,3), SHUF(ahi,0,0), h);
    l = __builtin_elementwise_fma(SHUF(c3,0,1), SHUF(ahi,1,1), l);
    h = __builtin_elementwise_fma(SHUF(c3,2,3), SHUF(ahi,1,1), h);
    lo = l; hi = h;
}

__global__ __launch_bounds__(256) void phylo_kernel(const float* __restrict__ X,
                                                    const float* __restrict__ ws,
                                                    float* __restrict__ out,
                                                    int batch)
{
    const int sraw = blockIdx.x * 256 + threadIdx.x;
    const int site = sraw < batch ? sraw : batch - 1;   // clamp, no divergent early-exit
    const v4f* __restrict__ P  = (const v4f*)ws;        // wave-uniform invariant reads -> s_load
    const v4f* __restrict__ xs = (const v4f*)X + (size_t)site * 20;

    v2f lo[MM], hi[MM];

    // ---- step 0: node 20 = (leaf0, leaf1) ----
    v4f xa = xs[0];
    v4f xb = xs[1];
    #pragma unroll
    for (int m = 0; m < MM; m++) {
        const v4f* __restrict__ P0 = P + (0*MM + m)*4;
        const v4f* __restrict__ P1 = P + (1*MM + m)*4;
        v2f tl, th, ul, uh;
        matvx(P0[0],P0[1],P0[2],P0[3], xa, tl, th);
        matvx(P1[0],P1[1],P1[2],P1[3], xb, ul, uh);
        lo[m] = tl*ul; hi[m] = th*uh;
    }

    // ---- steps 1..18: node 20+j = (internal 19+j, leaf j+1); double-buffered X ----
    xa = xs[2];                           // leaf for step j=1
    #pragma unroll 1
    for (int j = 1; j < KINT; j++) {
        xb = xa;
        if (j < KINT - 1) xb = xs[j + 2]; // prefetch next leaf (uniform branch)
        const v4f* __restrict__ PI = P + (2*j*MM)*4;   // internal-child block (uniform addr)
        const v4f* __restrict__ PL = PI + MM*4;        // leaf-child block
        #pragma unroll
        for (int m = 0; m < MM; m++) {
            v2f tl, th, ul, uh;
            matvs(PI[m*4+0],PI[m*4+1],PI[m*4+2],PI[m*4+3], lo[m], hi[m], tl, th);
            matvx(PL[m*4+0],PL[m*4+1],PL[m*4+2],PL[m*4+3], xa, ul, uh);
            lo[m] = tl*ul; hi[m] = th*uh;
        }
        xa = xb;
    }

    // ---- epilogue: out[site, m] = sum_c A[c] * pi[m][c] ----
    const v4f* __restrict__ pip = P + P4;
    float r[MM];
    #pragma unroll
    for (int m = 0; m < MM; m++) {
        v4f pim = pip[m];
        v2f s = __builtin_elementwise_fma(hi[m], SHUF(pim,2,3), lo[m] * SHUF(pim,0,1));
        r[m] = s.x + s.y;
    }
    if (sraw < batch) {
        v4f* __restrict__ o4 = (v4f*)(out + (size_t)sraw * MM);
        o4[0] = (v4f){r[0], r[1], r[2], r[3]};
        o4[1] = (v4f){r[4], r[5], r[6], r[7]};
    }
}

// ---------------- launch ----------------

extern "C" void kernel_launch(void* const* d_in, const int* in_sizes, int n_in,
                              void* d_out, int out_size, void* d_ws, size_t ws_size,
                              hipStream_t stream)
{
    const float* X      = (const float*)d_in[0];
    const float* rates  = (const float*)d_in[1];
    const float* pi_inv = (const float*)d_in[2];
    const float* rho    = (const float*)d_in[3];
    const float* T      = (const float*)d_in[4];
    float* out = (float*)d_out;
    float* ws  = (float*)d_ws;

    int batch = in_sizes[0] / (NLEAF * SS);

    hipLaunchKernelGGL(setup_kernel, dim3(1), dim3(320), 0, stream,
                       rates, pi_inv, rho, T, ws);

    int grid = (batch + 255) / 256;
    hipLaunchKernelGGL(phylo_kernel, dim3(grid), dim3(256), 0, stream,
                       X, ws, out, batch);
}